// Round 3
// baseline (306.026 us; speedup 1.0000x reference)
//
#include <hip/hip_runtime.h>
#include <math.h>

// ECE over softmax(logits[131072,1000]) — replicating the REFERENCE's fp32
// segment_sum saturation semantics:
//   - bin-0 cnt saturates exactly at 2^24 (adds of 1.0f freeze there)
//   - bin-0 conf_sum quasi-saturates (~74e3): in accumulator band [2^b,2^{b+1})
//     each add contributes rint(conf/ulp_b)*ulp_b. We measure empirical band
//     rates on a 1/16 ROW subsample (per-iteration, uniform across waves) and
//     integrate the mean-field walk in a tiny finalize kernel.

constexpr int N_ROWS  = 131072;
constexpr int N_COLS  = 1000;       // 250 float4 per row
constexpr int NBINS   = 15;
constexpr int NBANDS  = 9;          // accumulator exponent bands b = 10..18
constexpr int BAND_LO = 10;

// ws layout (doubles)
constexpr int WS_CNT  = 0;   // [1..14] high-bin counts
constexpr int WS_CSUM = 15;  // [16..29] high-bin conf sums
constexpr int WS_ASUM = 30;  // [31..44] high-bin acc sums
constexpr int WS_CS0  = 45;  // bin-0 exact conf sum (for mean rate mu)
constexpr int WS_ACC0 = 46;  // bin-0 acc count (label hits)
constexpr int WS_EXCL = 47;  // excluded real elements (conf==0 etc.)
constexpr int WS_NSUB = 48;  // subsampled bin-0 element count
constexpr int WS_BAND = 49;  // [49..57] band quantized-increment sums
constexpr int WS_N    = 58;

__global__ __launch_bounds__(256) void ece_pass(const float* __restrict__ logits,
                                                const int*   __restrict__ labels,
                                                double*      __restrict__ g,
                                                int n_rows) {
    __shared__ float    s_csum[NBINS];
    __shared__ unsigned s_cnt [NBINS];
    __shared__ unsigned s_asum[NBINS];
    const int tid = threadIdx.x;
    if (tid < NBINS) { s_csum[tid] = 0.f; s_cnt[tid] = 0u; s_asum[tid] = 0u; }
    __syncthreads();

    const int lane = tid & 63;
    const int wid  = tid >> 6;
    const int nwaves = gridDim.x * 4;
    const int gwave  = blockIdx.x * 4 + wid;
    const float delta = 1.0f / 15.0f;

    float    csum0 = 0.f;
    unsigned acc0 = 0u, excl = 0u, nsubc = 0u;
    float band[NBANDS];
    #pragma unroll
    for (int i = 0; i < NBANDS; ++i) band[i] = 0.f;

    int it = 0;
    for (int row = gwave; row < n_rows; row += nwaves, ++it) {
        const bool sub = (it & 15) == 0;   // uniform 1/16 row subsample PER WAVE
        const float4* rp = reinterpret_cast<const float4*>(logits + (size_t)row * N_COLS);
        const bool v3 = lane < 58;
        float4 a0 = rp[lane];
        float4 a1 = rp[64 + lane];
        float4 a2 = rp[128 + lane];
        float4 a3 = v3 ? rp[192 + lane] : float4{-1e30f, -1e30f, -1e30f, -1e30f};

        float x[16];
        x[0]=a0.x;  x[1]=a0.y;  x[2]=a0.z;  x[3]=a0.w;
        x[4]=a1.x;  x[5]=a1.y;  x[6]=a1.z;  x[7]=a1.w;
        x[8]=a2.x;  x[9]=a2.y;  x[10]=a2.z; x[11]=a2.w;
        x[12]=a3.x; x[13]=a3.y; x[14]=a3.z; x[15]=a3.w;

        float m = x[0];
        #pragma unroll
        for (int i = 1; i < 16; ++i) m = fmaxf(m, x[i]);
        #pragma unroll
        for (int off = 32; off >= 1; off >>= 1) m = fmaxf(m, __shfl_xor(m, off, 64));

        float s = 0.f;
        #pragma unroll
        for (int i = 0; i < 16; ++i) { float e = __expf(x[i] - m); x[i] = e; s += e; }
        #pragma unroll
        for (int off = 32; off >= 1; off >>= 1) s += __shfl_xor(s, off, 64);
        const float inv = 1.0f / s;

        const int label = labels[row];

        #pragma unroll
        for (int j = 0; j < 4; ++j) {
            #pragma unroll
            for (int q = 0; q < 4; ++q) {
                const int col = j * 256 + lane * 4 + q;
                if (col < N_COLS) {
                    const float conf = x[j * 4 + q] * inv;
                    // exact searchsorted(linspace(0,1,16),'left')-1 semantics
                    int k = (int)(conf * 15.0f);
                    if (k > 15) k = 15;
                    const float bk  = (float)k * delta;
                    const float bk1 = (float)(k + 1) * delta;
                    if (conf <= bk)      k -= 1;
                    else if (conf > bk1) k += 1;

                    const bool a = (col == label);
                    if (k == 0) {
                        csum0 += conf;
                        if (a) acc0 += 1u;
                        if (sub) {
                            nsubc += 1u;
                            #pragma unroll
                            for (int b = 0; b < NBANDS; ++b)
                                band[b] += rintf(conf * (float)(1 << (13 - b)));
                        }
                    } else if (k >= 1 && k < NBINS) {
                        atomicAdd(&s_cnt[k], 1u);
                        atomicAdd(&s_csum[k], conf);
                        if (a) atomicAdd(&s_asum[k], 1u);
                    } else {
                        excl += 1u;   // conf==0 (or >1): excluded by reference
                    }
                }
            }
        }
    }

    #pragma unroll
    for (int off = 32; off >= 1; off >>= 1) {
        csum0 += __shfl_xor(csum0, off, 64);
        acc0  += __shfl_xor(acc0,  off, 64);
        excl  += __shfl_xor(excl,  off, 64);
        nsubc += __shfl_xor(nsubc, off, 64);
        #pragma unroll
        for (int b = 0; b < NBANDS; ++b) band[b] += __shfl_xor(band[b], off, 64);
    }

    __shared__ float    rf[4][NBANDS + 1];
    __shared__ unsigned ru[4][3];
    if (lane == 0) {
        rf[wid][0] = csum0;
        #pragma unroll
        for (int b = 0; b < NBANDS; ++b) rf[wid][1 + b] = band[b];
        ru[wid][0] = acc0; ru[wid][1] = excl; ru[wid][2] = nsubc;
    }
    __syncthreads();

    if (tid == 0) {
        double cs = 0, a0d = 0, ex = 0, ns = 0, bd[NBANDS];
        for (int b = 0; b < NBANDS; ++b) bd[b] = 0.0;
        for (int w = 0; w < 4; ++w) {
            cs  += (double)rf[w][0];
            a0d += (double)ru[w][0];
            ex  += (double)ru[w][1];
            ns  += (double)ru[w][2];
            for (int b = 0; b < NBANDS; ++b) bd[b] += (double)rf[w][1 + b];
        }
        atomicAdd(&g[WS_CS0],  cs);
        atomicAdd(&g[WS_ACC0], a0d);
        atomicAdd(&g[WS_EXCL], ex);
        atomicAdd(&g[WS_NSUB], ns);
        for (int b = 0; b < NBANDS; ++b) atomicAdd(&g[WS_BAND + b], bd[b]);
    }
    if (tid >= 1 && tid < NBINS) {
        if (s_cnt[tid]) {
            atomicAdd(&g[WS_CNT  + tid], (double)s_cnt[tid]);
            atomicAdd(&g[WS_CSUM + tid], (double)s_csum[tid]);
            atomicAdd(&g[WS_ASUM + tid], (double)s_asum[tid]);
        }
    }
}

__global__ void ece_final(const double* __restrict__ g, float* __restrict__ out) {
    if (threadIdx.x != 0 || blockIdx.x != 0) return;
    const double total = 131072000.0;

    double hi_cnt = 0.0;
    for (int k = 1; k < NBINS; ++k) hi_cnt += g[WS_CNT + k];
    const double n0 = total - hi_cnt - g[WS_EXCL];
    const double mu = (n0 > 0.0) ? g[WS_CS0] / n0 : 0.0;
    const double nsub = g[WS_NSUB];

    double rate[NBANDS];
    for (int b = 0; b < NBANDS; ++b)
        rate[b] = (nsub > 0.0) ? (g[WS_BAND + b] / nsub) * ldexp(1.0, (BAND_LO + b) - 23)
                               : mu;

    // mean-field walk of the fp32 sequential accumulator
    double acc = 0.0, rem = n0;
    for (int it = 0; it < 64 && rem > 0.5; ++it) {
        double r, edge;
        if (acc < 1024.0) { r = mu; edge = 1024.0; }    // sub-2^10: rounding bias negligible
        else {
            int b = BAND_LO;
            while (b < BAND_LO + NBANDS - 1 && acc >= ldexp(1.0, b + 1)) ++b;
            r = rate[b - BAND_LO];
            edge = (b == BAND_LO + NBANDS - 1) ? 1e300 : ldexp(1.0, b + 1);
        }
        if (!(r > 1e-300)) break;                        // accumulator frozen
        const double need = (edge - acc) / r;
        if (need >= rem) { acc += rem * r; rem = 0.0; }
        else             { acc = edge; rem -= need; }
    }
    const double conf_sum0 = acc;
    const double cnt0 = (n0 < 16777216.0) ? n0 : 16777216.0;  // fp32 +1.0 saturation

    double ece = 0.0;
    if (cnt0 > 0.0)
        ece += fabs(conf_sum0 / cnt0 - g[WS_ACC0] / cnt0) * (cnt0 / total);
    for (int k = 1; k < NBINS; ++k) {
        const double c = g[WS_CNT + k];
        if (c > 0.0)
            ece += fabs(g[WS_CSUM + k] / c - g[WS_ASUM + k] / c) * (c / total);
    }
    out[0] = (float)ece;
}

extern "C" void kernel_launch(void* const* d_in, const int* in_sizes, int n_in,
                              void* d_out, int out_size, void* d_ws, size_t ws_size,
                              hipStream_t stream) {
    const float* logits = (const float*)d_in[0];
    const int*   labels = (const int*)d_in[1];
    float*       out    = (float*)d_out;
    double*      g      = (double*)d_ws;

    hipMemsetAsync(g, 0, WS_N * sizeof(double), stream);

    const int blocks = 2048;   // 8192 waves, 16 rows/wave (exact)
    ece_pass<<<blocks, 256, 0, stream>>>(logits, labels, g, N_ROWS);
    ece_final<<<1, 64, 0, stream>>>(g, out);
}

// Round 4
// 195.742 us; speedup vs baseline: 1.5634x; 1.5634x over previous
//
#include <hip/hip_runtime.h>
#include <math.h>

// ECE over softmax(logits[131072,1000]) replicating the reference's fp32
// segment_sum saturation (bin-0 cnt freezes at 2^24; conf_sum quasi-saturates
// ~74e3, reproduced via measured per-band quantized rates + mean-field walk).
// Hot loop is specialized for the all-bin-0 common case with an exact
// reference-semantics fallback per row (any conf > 1/15, any conf == 0/NaN).

constexpr int N_ROWS  = 131072;
constexpr int N_COLS  = 1000;       // 250 float4 per row
constexpr int NBINS   = 15;
constexpr int NBANDS  = 9;          // accumulator exponent bands b = 10..18
constexpr int BAND_LO = 10;

// ws layout (doubles)
constexpr int WS_CNT  = 0;   // [1..14] high-bin counts
constexpr int WS_CSUM = 15;  // [16..29] high-bin conf sums
constexpr int WS_ASUM = 30;  // [31..44] high-bin acc sums
constexpr int WS_CS0  = 45;  // bin-0 exact conf sum (for mean rate mu)
constexpr int WS_ACC0 = 46;  // bin-0 acc count (label hits)
constexpr int WS_EXCL = 47;  // excluded elements (conf==0 or bin>=15)
constexpr int WS_NSUB = 48;  // subsampled bin-0 element count
constexpr int WS_BAND = 49;  // [49..57] band quantized-increment sums
constexpr int WS_N    = 58;

__device__ __forceinline__ float wave_fsum(float v) {
    #pragma unroll
    for (int off = 32; off >= 1; off >>= 1) v += __shfl_xor(v, off, 64);
    return v;
}
__device__ __forceinline__ float wave_fmax(float v) {
    #pragma unroll
    for (int off = 32; off >= 1; off >>= 1) v = fmaxf(v, __shfl_xor(v, off, 64));
    return v;
}
__device__ __forceinline__ unsigned wave_usum(unsigned v) {
    #pragma unroll
    for (int off = 32; off >= 1; off >>= 1) v += (unsigned)__shfl_xor((int)v, off, 64);
    return v;
}

__global__ __launch_bounds__(256) void ece_pass(const float* __restrict__ logits,
                                                const int*   __restrict__ labels,
                                                double*      __restrict__ g,
                                                int n_rows) {
    __shared__ float    s_csum[NBINS];
    __shared__ unsigned s_cnt [NBINS];
    __shared__ unsigned s_asum[NBINS];
    const int tid = threadIdx.x;
    if (tid < NBINS) { s_csum[tid] = 0.f; s_cnt[tid] = 0u; s_asum[tid] = 0u; }
    __syncthreads();

    const int lane = tid & 63;
    const int wid  = tid >> 6;
    const int nwaves = gridDim.x << 2;
    const int gwave  = (blockIdx.x << 2) | wid;
    const float delta = 1.0f / 15.0f;
    const bool v3 = lane < 58;                   // 4th float4 valid (250 = 64*3 + 58)
    const float4 PAD = make_float4(-1e30f, -1e30f, -1e30f, -1e30f);

    float    csum0 = 0.f;
    unsigned acc0 = 0u, excl = 0u, nsubc = 0u;
    float band[NBANDS];
    #pragma unroll
    for (int b = 0; b < NBANDS; ++b) band[b] = 0.f;

    // ---- software-pipelined row loop (prefetch next row) ----
    int row = gwave;
    float4 a0, a1, a2, a3; int lab = 0;
    if (row < n_rows) {
        const float4* rp = reinterpret_cast<const float4*>(logits + (size_t)row * N_COLS);
        a0 = rp[lane]; a1 = rp[64 + lane]; a2 = rp[128 + lane];
        a3 = v3 ? rp[192 + lane] : PAD;
        lab = labels[row];
    }

    int it = 0;
    while (row < n_rows) {
        const int nrow = row + nwaves;
        float4 b0, b1, b2, b3; int nlab = 0;
        if (nrow < n_rows) {
            const float4* rp = reinterpret_cast<const float4*>(logits + (size_t)nrow * N_COLS);
            b0 = rp[lane]; b1 = rp[64 + lane]; b2 = rp[128 + lane];
            b3 = v3 ? rp[192 + lane] : PAD;
            nlab = labels[nrow];
        }
        const bool sub = (it & 15) == 0;         // uniform 1/16 row subsample (8192 rows)

        // exp(x) directly (softmax is shift-invariant; overflow/underflow -> rare path)
        float ev[16];
        ev[0]=__expf(a0.x); ev[1]=__expf(a0.y); ev[2]=__expf(a0.z); ev[3]=__expf(a0.w);
        ev[4]=__expf(a1.x); ev[5]=__expf(a1.y); ev[6]=__expf(a1.z); ev[7]=__expf(a1.w);
        ev[8]=__expf(a2.x); ev[9]=__expf(a2.y); ev[10]=__expf(a2.z); ev[11]=__expf(a2.w);
        ev[12]=__expf(a3.x); ev[13]=__expf(a3.y); ev[14]=__expf(a3.z); ev[15]=__expf(a3.w);

        const float q0 = (ev[0]+ev[1])+(ev[2]+ev[3]);
        const float q1 = (ev[4]+ev[5])+(ev[6]+ev[7]);
        const float q2 = (ev[8]+ev[9])+(ev[10]+ev[11]);
        const float q3 = (ev[12]+ev[13])+(ev[14]+ev[15]);
        const float s   = wave_fsum((q0+q1)+(q2+q3));
        const float inv = 1.0f / s;

        float cf[16];
        #pragma unroll
        for (int i = 0; i < 16; ++i) cf[i] = ev[i] * inv;

        // row classification: any conf > delta, or any conf==0/NaN among valid cols
        const float x01=fmaxf(cf[0],cf[1]), x23=fmaxf(cf[2],cf[3]);
        const float x45=fmaxf(cf[4],cf[5]), x67=fmaxf(cf[6],cf[7]);
        const float x89=fmaxf(cf[8],cf[9]), xab=fmaxf(cf[10],cf[11]);
        const float xcd=fmaxf(cf[12],cf[13]), xef=fmaxf(cf[14],cf[15]);
        const float mx = fmaxf(fmaxf(fmaxf(x01,x23),fmaxf(x45,x67)),
                               fmaxf(fmaxf(x89,xab),fmaxf(xcd,xef)));
        const float n01=fminf(cf[0],cf[1]), n23=fminf(cf[2],cf[3]);
        const float n45=fminf(cf[4],cf[5]), n67=fminf(cf[6],cf[7]);
        const float n89=fminf(cf[8],cf[9]), nab=fminf(cf[10],cf[11]);
        const float mnA = fminf(fminf(fminf(n01,n23),fminf(n45,n67)),fminf(n89,nab));
        const float mnB = fminf(fminf(cf[12],cf[13]),fminf(cf[14],cf[15]));
        const float mn  = fminf(mnA, v3 ? mnB : 1.0f);
        const bool rare = __any((mx > delta) || !(mn > 0.0f));

        if (__builtin_expect(!rare, 1)) {
            // all valid elements are bin 0
            const float c0=(cf[0]+cf[1])+(cf[2]+cf[3]);
            const float c1=(cf[4]+cf[5])+(cf[6]+cf[7]);
            const float c2=(cf[8]+cf[9])+(cf[10]+cf[11]);
            const float c3=(cf[12]+cf[13])+(cf[14]+cf[15]);
            csum0 += (c0+c1)+(c2+c3);
            if (lane == ((lab >> 2) & 63)) acc0 += 1u;   // label element is bin 0
            if (sub) {
                nsubc += v3 ? 16u : 12u;
                #pragma unroll
                for (int b = 0; b < NBANDS; ++b) {
                    const float c = (float)(1 << (13 - b));
                    const float r0=(rintf(cf[0]*c)+rintf(cf[1]*c))+(rintf(cf[2]*c)+rintf(cf[3]*c));
                    const float r1=(rintf(cf[4]*c)+rintf(cf[5]*c))+(rintf(cf[6]*c)+rintf(cf[7]*c));
                    const float r2=(rintf(cf[8]*c)+rintf(cf[9]*c))+(rintf(cf[10]*c)+rintf(cf[11]*c));
                    const float r3=(rintf(cf[12]*c)+rintf(cf[13]*c))+(rintf(cf[14]*c)+rintf(cf[15]*c));
                    band[b] += (r0+r1)+(r2+r3);
                }
            }
        } else {
            // exact reference-semantics redo of this row (max-subtracted softmax)
            float x[16];
            x[0]=a0.x; x[1]=a0.y; x[2]=a0.z; x[3]=a0.w;
            x[4]=a1.x; x[5]=a1.y; x[6]=a1.z; x[7]=a1.w;
            x[8]=a2.x; x[9]=a2.y; x[10]=a2.z; x[11]=a2.w;
            x[12]=a3.x; x[13]=a3.y; x[14]=a3.z; x[15]=a3.w;
            float m = x[0];
            #pragma unroll
            for (int i = 1; i < 16; ++i) m = fmaxf(m, x[i]);
            m = wave_fmax(m);
            float e2[16], s2 = 0.f;
            #pragma unroll
            for (int i = 0; i < 16; ++i) { e2[i] = __expf(x[i] - m); s2 += e2[i]; }
            s2 = wave_fsum(s2);
            const float inv2 = 1.0f / s2;
            #pragma unroll
            for (int i = 0; i < 16; ++i) {
                const int col = (i >> 2) * 256 + lane * 4 + (i & 3);
                if (col < N_COLS) {
                    const float conf = e2[i] * inv2;
                    int k = (int)(conf * 15.0f);
                    if (k > 15) k = 15;
                    const float bk  = (float)k * delta;
                    const float bk1 = (float)(k + 1) * delta;
                    if (conf <= bk)      k -= 1;
                    else if (conf > bk1) k += 1;
                    const bool a = (col == lab);
                    if (k == 0) {
                        csum0 += conf;
                        if (a) acc0 += 1u;
                        if (sub) {
                            nsubc += 1u;
                            #pragma unroll
                            for (int b = 0; b < NBANDS; ++b)
                                band[b] += rintf(conf * (float)(1 << (13 - b)));
                        }
                    } else if (k >= 1 && k < NBINS) {
                        atomicAdd(&s_cnt[k], 1u);
                        atomicAdd(&s_csum[k], conf);
                        if (a) atomicAdd(&s_asum[k], 1u);
                    } else {
                        excl += 1u;   // conf==0 or bin>=15: excluded by reference
                    }
                }
            }
        }

        a0 = b0; a1 = b1; a2 = b2; a3 = b3; lab = nlab;
        row = nrow; ++it;
    }

    // ---- wave / block / global reduction ----
    csum0 = wave_fsum(csum0);
    #pragma unroll
    for (int b = 0; b < NBANDS; ++b) band[b] = wave_fsum(band[b]);
    acc0 = wave_usum(acc0); excl = wave_usum(excl); nsubc = wave_usum(nsubc);

    __shared__ float    rf[4][NBANDS + 1];
    __shared__ unsigned ru[4][3];
    if (lane == 0) {
        rf[wid][0] = csum0;
        #pragma unroll
        for (int b = 0; b < NBANDS; ++b) rf[wid][1 + b] = band[b];
        ru[wid][0] = acc0; ru[wid][1] = excl; ru[wid][2] = nsubc;
    }
    __syncthreads();

    if (tid == 0) {
        double cs = 0, a0d = 0, ex = 0, ns = 0, bd[NBANDS];
        for (int b = 0; b < NBANDS; ++b) bd[b] = 0.0;
        for (int w = 0; w < 4; ++w) {
            cs  += (double)rf[w][0];
            a0d += (double)ru[w][0];
            ex  += (double)ru[w][1];
            ns  += (double)ru[w][2];
            for (int b = 0; b < NBANDS; ++b) bd[b] += (double)rf[w][1 + b];
        }
        atomicAdd(&g[WS_CS0],  cs);
        atomicAdd(&g[WS_ACC0], a0d);
        atomicAdd(&g[WS_EXCL], ex);
        atomicAdd(&g[WS_NSUB], ns);
        for (int b = 0; b < NBANDS; ++b) atomicAdd(&g[WS_BAND + b], bd[b]);
    }
    if (tid >= 1 && tid < NBINS) {
        if (s_cnt[tid]) {
            atomicAdd(&g[WS_CNT  + tid], (double)s_cnt[tid]);
            atomicAdd(&g[WS_CSUM + tid], (double)s_csum[tid]);
            atomicAdd(&g[WS_ASUM + tid], (double)s_asum[tid]);
        }
    }
}

__global__ void ece_final(const double* __restrict__ g, float* __restrict__ out) {
    if (threadIdx.x != 0 || blockIdx.x != 0) return;
    const double total = 131072000.0;

    double hi_cnt = 0.0;
    for (int k = 1; k < NBINS; ++k) hi_cnt += g[WS_CNT + k];
    const double n0 = total - hi_cnt - g[WS_EXCL];
    const double mu = (n0 > 0.0) ? g[WS_CS0] / n0 : 0.0;
    const double nsub = g[WS_NSUB];

    double rate[NBANDS];
    for (int b = 0; b < NBANDS; ++b)
        rate[b] = (nsub > 0.0) ? (g[WS_BAND + b] / nsub) * ldexp(1.0, (BAND_LO + b) - 23)
                               : mu;

    // mean-field walk of the reference's fp32 sequential accumulator
    double acc = 0.0, rem = n0;
    for (int itr = 0; itr < 64 && rem > 0.5; ++itr) {
        double r, edge;
        if (acc < 1024.0) { r = mu; edge = 1024.0; }
        else {
            int b = BAND_LO;
            while (b < BAND_LO + NBANDS - 1 && acc >= ldexp(1.0, b + 1)) ++b;
            r = rate[b - BAND_LO];
            edge = (b == BAND_LO + NBANDS - 1) ? 1e300 : ldexp(1.0, b + 1);
        }
        if (!(r > 1e-300)) break;                 // accumulator frozen
        const double need = (edge - acc) / r;
        if (need >= rem) { acc += rem * r; rem = 0.0; }
        else             { acc = edge; rem -= need; }
    }
    const double conf_sum0 = acc;
    const double cnt0 = (n0 < 16777216.0) ? n0 : 16777216.0;  // fp32 +1.0 saturation

    double ece = 0.0;
    if (cnt0 > 0.0)
        ece += fabs(conf_sum0 / cnt0 - g[WS_ACC0] / cnt0) * (cnt0 / total);
    for (int k = 1; k < NBINS; ++k) {
        const double c = g[WS_CNT + k];
        if (c > 0.0)
            ece += fabs(g[WS_CSUM + k] / c - g[WS_ASUM + k] / c) * (c / total);
    }
    out[0] = (float)ece;
}

extern "C" void kernel_launch(void* const* d_in, const int* in_sizes, int n_in,
                              void* d_out, int out_size, void* d_ws, size_t ws_size,
                              hipStream_t stream) {
    const float* logits = (const float*)d_in[0];
    const int*   labels = (const int*)d_in[1];
    float*       out    = (float*)d_out;
    double*      g      = (double*)d_ws;

    hipMemsetAsync(g, 0, WS_N * sizeof(double), stream);

    const int blocks = 1024;   // 4096 waves, 32 rows/wave (exact) — R2-proven best
    ece_pass<<<blocks, 256, 0, stream>>>(logits, labels, g, N_ROWS);
    ece_final<<<1, 64, 0, stream>>>(g, out);
}

// Round 5
// 179.309 us; speedup vs baseline: 1.7067x; 1.0916x over previous
//
#include <hip/hip_runtime.h>
#include <math.h>

// ECE over softmax(logits[131072,1000]) replicating the reference's fp32
// segment_sum saturation (bin-0 cnt freezes at 2^24; conf_sum quasi-saturates
// ~74e3, reproduced via measured per-band quantized rates + mean-field walk).
// Hot loop: 2 rows per iteration (independent ILP chains), 2-row prefetch,
// ev-domain classification; exact reference-semantics fallback per rare row
// (any conf > 1/15, any conf == 0/NaN) which reloads its row from global.

constexpr int N_ROWS  = 131072;
constexpr int N_COLS  = 1000;       // 250 float4 per row
constexpr int NBINS   = 15;
constexpr int NBANDS  = 9;          // accumulator exponent bands b = 10..18
constexpr int BAND_LO = 10;

constexpr int BLOCKS  = 1024;
constexpr int NWAVES  = BLOCKS * 4;            // 4096 waves
constexpr int NPAIRS  = N_ROWS / (2 * NWAVES); // 16 pair-iterations per wave (exact)

// ws layout (doubles)
constexpr int WS_CNT  = 0;   // [1..14] high-bin counts
constexpr int WS_CSUM = 15;  // [16..29] high-bin conf sums
constexpr int WS_ASUM = 30;  // [31..44] high-bin acc sums
constexpr int WS_CS0  = 45;  // bin-0 exact conf sum (for mean rate mu)
constexpr int WS_ACC0 = 46;  // bin-0 acc count (label hits)
constexpr int WS_EXCL = 47;  // excluded elements (conf==0 or bin>=15)
constexpr int WS_NSUB = 48;  // subsampled bin-0 element count
constexpr int WS_BAND = 49;  // [49..57] band quantized-increment sums
constexpr int WS_N    = 58;

__device__ __forceinline__ float wave_fsum(float v) {
    #pragma unroll
    for (int off = 32; off >= 1; off >>= 1) v += __shfl_xor(v, off, 64);
    return v;
}
__device__ __forceinline__ float wave_fmax(float v) {
    #pragma unroll
    for (int off = 32; off >= 1; off >>= 1) v = fmaxf(v, __shfl_xor(v, off, 64));
    return v;
}
__device__ __forceinline__ unsigned wave_usum(unsigned v) {
    #pragma unroll
    for (int off = 32; off >= 1; off >>= 1) v += (unsigned)__shfl_xor((int)v, off, 64);
    return v;
}

__device__ __forceinline__ void load_row(const float* __restrict__ logits,
                                         const int*   __restrict__ labels,
                                         int row, int lane, bool v3,
                                         float4& r0, float4& r1, float4& r2, float4& r3, int& lb) {
    const float4* rp = reinterpret_cast<const float4*>(logits + (size_t)row * N_COLS);
    r0 = rp[lane]; r1 = rp[64 + lane]; r2 = rp[128 + lane];
    r3 = v3 ? rp[192 + lane] : make_float4(-1e30f, -1e30f, -1e30f, -1e30f);
    lb = labels[row];
}

// common-case core: exp, lane-sum, wave-sum, ev-domain classification
__device__ __forceinline__ void row_core(float4 A0, float4 A1, float4 A2, float4 A3, bool v3,
                                         float ev[16], float& q, float& inv, bool& rare) {
    ev[0]=__expf(A0.x);  ev[1]=__expf(A0.y);  ev[2]=__expf(A0.z);  ev[3]=__expf(A0.w);
    ev[4]=__expf(A1.x);  ev[5]=__expf(A1.y);  ev[6]=__expf(A1.z);  ev[7]=__expf(A1.w);
    ev[8]=__expf(A2.x);  ev[9]=__expf(A2.y);  ev[10]=__expf(A2.z); ev[11]=__expf(A2.w);
    ev[12]=__expf(A3.x); ev[13]=__expf(A3.y); ev[14]=__expf(A3.z); ev[15]=__expf(A3.w);

    const float q0 = (ev[0]+ev[1])+(ev[2]+ev[3]);
    const float q1 = (ev[4]+ev[5])+(ev[6]+ev[7]);
    const float q2 = (ev[8]+ev[9])+(ev[10]+ev[11]);
    const float q3 = (ev[12]+ev[13])+(ev[14]+ev[15]);
    q = (q0+q1)+(q2+q3);
    const float s = wave_fsum(q);
    inv = 1.0f / s;

    // max over all (padding ev==0 can't win), min over valid only
    const float x01=fmaxf(ev[0],ev[1]),  x23=fmaxf(ev[2],ev[3]);
    const float x45=fmaxf(ev[4],ev[5]),  x67=fmaxf(ev[6],ev[7]);
    const float x89=fmaxf(ev[8],ev[9]),  xab=fmaxf(ev[10],ev[11]);
    const float xcd=fmaxf(ev[12],ev[13]),xef=fmaxf(ev[14],ev[15]);
    const float mx = fmaxf(fmaxf(fmaxf(x01,x23),fmaxf(x45,x67)),
                           fmaxf(fmaxf(x89,xab),fmaxf(xcd,xef)));
    const float n01=fminf(ev[0],ev[1]),  n23=fminf(ev[2],ev[3]);
    const float n45=fminf(ev[4],ev[5]),  n67=fminf(ev[6],ev[7]);
    const float n89=fminf(ev[8],ev[9]),  nab=fminf(ev[10],ev[11]);
    const float mnA = fminf(fminf(fminf(n01,n23),fminf(n45,n67)),fminf(n89,nab));
    const float mnB = fminf(fminf(ev[12],ev[13]),fminf(ev[14],ev[15]));
    const float mn  = v3 ? fminf(mnA, mnB) : mnA;

    const float DELTA = 1.0f / 15.0f;
    // mx*inv == max conf (rounding monotone); s==NaN/Inf propagates into both tests
    rare = __any((mx * inv > DELTA) || !(mn * inv > 0.0f));
}

// cold exact path: reference searchsorted semantics, max-subtracted softmax
__device__ void rare_row(const float* __restrict__ logits, int row, int lab,
                         bool sub, int lane, bool v3,
                         float& csum0, unsigned& acc0, unsigned& excl, unsigned& nsubc,
                         float band[NBANDS],
                         float* s_csum, unsigned* s_cnt, unsigned* s_asum) {
    const float delta = 1.0f / 15.0f;
    const float4* rp = reinterpret_cast<const float4*>(logits + (size_t)row * N_COLS);
    float4 a0 = rp[lane], a1 = rp[64 + lane], a2 = rp[128 + lane];
    float4 a3 = v3 ? rp[192 + lane] : make_float4(-1e30f, -1e30f, -1e30f, -1e30f);
    float x[16] = {a0.x,a0.y,a0.z,a0.w, a1.x,a1.y,a1.z,a1.w,
                   a2.x,a2.y,a2.z,a2.w, a3.x,a3.y,a3.z,a3.w};
    float m = x[0];
    #pragma unroll
    for (int i = 1; i < 16; ++i) m = fmaxf(m, x[i]);
    m = wave_fmax(m);
    float e2[16], s2 = 0.f;
    #pragma unroll
    for (int i = 0; i < 16; ++i) { e2[i] = __expf(x[i] - m); s2 += e2[i]; }
    s2 = wave_fsum(s2);
    const float inv2 = 1.0f / s2;
    #pragma unroll
    for (int i = 0; i < 16; ++i) {
        const int col = (i >> 2) * 256 + lane * 4 + (i & 3);
        if (col < N_COLS) {
            const float conf = e2[i] * inv2;
            int k = (int)(conf * 15.0f);
            if (k > 15) k = 15;
            const float bk  = (float)k * delta;
            const float bk1 = (float)(k + 1) * delta;
            if (conf <= bk)      k -= 1;
            else if (conf > bk1) k += 1;
            const bool a = (col == lab);
            if (k == 0) {
                csum0 += conf;
                if (a) acc0 += 1u;
                if (sub) {
                    nsubc += 1u;
                    #pragma unroll
                    for (int b = 0; b < NBANDS; ++b)
                        band[b] += rintf(conf * (float)(1 << (13 - b)));
                }
            } else if (k >= 1 && k < NBINS) {
                atomicAdd(&s_cnt[k], 1u);
                atomicAdd(&s_csum[k], conf);
                if (a) atomicAdd(&s_asum[k], 1u);
            } else {
                excl += 1u;   // conf==0 or bin>=15: excluded by reference
            }
        }
    }
}

__global__ __launch_bounds__(256, 4) void ece_pass(const float* __restrict__ logits,
                                                   const int*   __restrict__ labels,
                                                   double*      __restrict__ g) {
    __shared__ float    s_csum[NBINS];
    __shared__ unsigned s_cnt [NBINS];
    __shared__ unsigned s_asum[NBINS];
    const int tid = threadIdx.x;
    if (tid < NBINS) { s_csum[tid] = 0.f; s_cnt[tid] = 0u; s_asum[tid] = 0u; }
    __syncthreads();

    const int lane = tid & 63;
    const int wid  = tid >> 6;
    const int gwave = (blockIdx.x << 2) | wid;
    const bool v3 = lane < 58;                  // 250 = 64*3 + 58

    float    csum0 = 0.f;
    unsigned acc0 = 0u, excl = 0u, nsubc = 0u;
    float band[NBANDS];
    #pragma unroll
    for (int b = 0; b < NBANDS; ++b) band[b] = 0.f;

    // pair k: rows gwave + (2k)*NWAVES and gwave + (2k+1)*NWAVES  (exact fit)
    int rowA = gwave;
    int rowB = gwave + NWAVES;
    float4 A0,A1,A2,A3, B0,B1,B2,B3; int labA, labB;
    load_row(logits, labels, rowA, lane, v3, A0,A1,A2,A3, labA);
    load_row(logits, labels, rowB, lane, v3, B0,B1,B2,B3, labB);

    for (int itp = 0; itp < NPAIRS; ++itp) {
        // prefetch next pair while computing this one
        float4 C0,C1,C2,C3, D0,D1,D2,D3; int labC = 0, labD = 0;
        const int rowC = rowA + 2 * NWAVES;
        const int rowD = rowB + 2 * NWAVES;
        if (itp + 1 < NPAIRS) {
            load_row(logits, labels, rowC, lane, v3, C0,C1,C2,C3, labC);
            load_row(logits, labels, rowD, lane, v3, D0,D1,D2,D3, labD);
        }

        float evA[16], evB[16];
        float qA, invA, qB, invB;
        bool rareA, rareB;
        row_core(A0,A1,A2,A3, v3, evA, qA, invA, rareA);
        row_core(B0,B1,B2,B3, v3, evB, qB, invB, rareB);

        const bool sub = (itp & 7) == 0;        // rows A of itp 0,8 -> 8192 rows = 1/16

        if (!rareA) {
            csum0 += qA * invA;
            if (lane == ((labA >> 2) & 63)) acc0 += 1u;
            if (sub) {
                nsubc += v3 ? 16u : 12u;
                float cf[16];
                #pragma unroll
                for (int i = 0; i < 16; ++i) cf[i] = evA[i] * invA;   // padding -> 0 -> rint 0
                #pragma unroll
                for (int b = 0; b < NBANDS; ++b) {
                    const float c = (float)(1 << (13 - b));
                    const float r0=(rintf(cf[0]*c)+rintf(cf[1]*c))+(rintf(cf[2]*c)+rintf(cf[3]*c));
                    const float r1=(rintf(cf[4]*c)+rintf(cf[5]*c))+(rintf(cf[6]*c)+rintf(cf[7]*c));
                    const float r2=(rintf(cf[8]*c)+rintf(cf[9]*c))+(rintf(cf[10]*c)+rintf(cf[11]*c));
                    const float r3=(rintf(cf[12]*c)+rintf(cf[13]*c))+(rintf(cf[14]*c)+rintf(cf[15]*c));
                    band[b] += (r0+r1)+(r2+r3);
                }
            }
        }
        if (!rareB) {
            csum0 += qB * invB;
            if (lane == ((labB >> 2) & 63)) acc0 += 1u;
        }
        if (__builtin_expect(rareA || rareB, 0)) {
            if (rareA) rare_row(logits, rowA, labA, sub,   lane, v3, csum0, acc0, excl, nsubc, band, s_csum, s_cnt, s_asum);
            if (rareB) rare_row(logits, rowB, labB, false, lane, v3, csum0, acc0, excl, nsubc, band, s_csum, s_cnt, s_asum);
        }

        A0=C0; A1=C1; A2=C2; A3=C3; labA=labC; rowA=rowC;
        B0=D0; B1=D1; B2=D2; B3=D3; labB=labD; rowB=rowD;
    }

    // ---- wave / block / global reduction ----
    csum0 = wave_fsum(csum0);
    #pragma unroll
    for (int b = 0; b < NBANDS; ++b) band[b] = wave_fsum(band[b]);
    acc0 = wave_usum(acc0); excl = wave_usum(excl); nsubc = wave_usum(nsubc);

    __shared__ float    rf[4][NBANDS + 1];
    __shared__ unsigned ru[4][3];
    if (lane == 0) {
        rf[wid][0] = csum0;
        #pragma unroll
        for (int b = 0; b < NBANDS; ++b) rf[wid][1 + b] = band[b];
        ru[wid][0] = acc0; ru[wid][1] = excl; ru[wid][2] = nsubc;
    }
    __syncthreads();

    if (tid == 0) {
        double cs = 0, a0d = 0, ex = 0, ns = 0, bd[NBANDS];
        for (int b = 0; b < NBANDS; ++b) bd[b] = 0.0;
        for (int w = 0; w < 4; ++w) {
            cs  += (double)rf[w][0];
            a0d += (double)ru[w][0];
            ex  += (double)ru[w][1];
            ns  += (double)ru[w][2];
            for (int b = 0; b < NBANDS; ++b) bd[b] += (double)rf[w][1 + b];
        }
        atomicAdd(&g[WS_CS0],  cs);
        atomicAdd(&g[WS_ACC0], a0d);
        atomicAdd(&g[WS_EXCL], ex);
        atomicAdd(&g[WS_NSUB], ns);
        for (int b = 0; b < NBANDS; ++b) atomicAdd(&g[WS_BAND + b], bd[b]);
    }
    if (tid >= 1 && tid < NBINS) {
        if (s_cnt[tid]) {
            atomicAdd(&g[WS_CNT  + tid], (double)s_cnt[tid]);
            atomicAdd(&g[WS_CSUM + tid], (double)s_csum[tid]);
            atomicAdd(&g[WS_ASUM + tid], (double)s_asum[tid]);
        }
    }
}

__global__ void ece_final(const double* __restrict__ g, float* __restrict__ out) {
    if (threadIdx.x != 0 || blockIdx.x != 0) return;
    const double total = 131072000.0;

    double hi_cnt = 0.0;
    for (int k = 1; k < NBINS; ++k) hi_cnt += g[WS_CNT + k];
    const double n0 = total - hi_cnt - g[WS_EXCL];
    const double mu = (n0 > 0.0) ? g[WS_CS0] / n0 : 0.0;
    const double nsub = g[WS_NSUB];

    double rate[NBANDS];
    for (int b = 0; b < NBANDS; ++b)
        rate[b] = (nsub > 0.0) ? (g[WS_BAND + b] / nsub) * ldexp(1.0, (BAND_LO + b) - 23)
                               : mu;

    // mean-field walk of the reference's fp32 sequential accumulator
    double acc = 0.0, rem = n0;
    for (int itr = 0; itr < 64 && rem > 0.5; ++itr) {
        double r, edge;
        if (acc < 1024.0) { r = mu; edge = 1024.0; }
        else {
            int b = BAND_LO;
            while (b < BAND_LO + NBANDS - 1 && acc >= ldexp(1.0, b + 1)) ++b;
            r = rate[b - BAND_LO];
            edge = (b == BAND_LO + NBANDS - 1) ? 1e300 : ldexp(1.0, b + 1);
        }
        if (!(r > 1e-300)) break;                 // accumulator frozen
        const double need = (edge - acc) / r;
        if (need >= rem) { acc += rem * r; rem = 0.0; }
        else             { acc = edge; rem -= need; }
    }
    const double conf_sum0 = acc;
    const double cnt0 = (n0 < 16777216.0) ? n0 : 16777216.0;  // fp32 +1.0 saturation

    double ece = 0.0;
    if (cnt0 > 0.0)
        ece += fabs(conf_sum0 / cnt0 - g[WS_ACC0] / cnt0) * (cnt0 / total);
    for (int k = 1; k < NBINS; ++k) {
        const double c = g[WS_CNT + k];
        if (c > 0.0)
            ece += fabs(g[WS_CSUM + k] / c - g[WS_ASUM + k] / c) * (c / total);
    }
    out[0] = (float)ece;
}

extern "C" void kernel_launch(void* const* d_in, const int* in_sizes, int n_in,
                              void* d_out, int out_size, void* d_ws, size_t ws_size,
                              hipStream_t stream) {
    const float* logits = (const float*)d_in[0];
    const int*   labels = (const int*)d_in[1];
    float*       out    = (float*)d_out;
    double*      g      = (double*)d_ws;

    hipMemsetAsync(g, 0, WS_N * sizeof(double), stream);

    ece_pass<<<BLOCKS, 256, 0, stream>>>(logits, labels, g);
    ece_final<<<1, 64, 0, stream>>>(g, out);
}

// Round 6
// 177.911 us; speedup vs baseline: 1.7201x; 1.0079x over previous
//
#include <hip/hip_runtime.h>
#include <math.h>

// ECE over softmax(logits[131072,1000]) replicating the reference's fp32
// segment_sum saturation (bin-0 cnt freezes at 2^24; conf_sum quasi-saturates
// ~74e3, reproduced via measured per-band quantized rates + mean-field walk).
// Hot loop: register-lean (exp values folded into running sum/max/min trees,
// no ev/cf arrays), 2 rows per iteration, 2-row-ahead prefetch. Subsample
// band stats and rare rows reload their row from global (cold paths).

constexpr int N_ROWS  = 131072;
constexpr int N_COLS  = 1000;       // 250 float4 per row
constexpr int NBINS   = 15;
constexpr int NBANDS  = 9;          // accumulator exponent bands b = 10..18
constexpr int BAND_LO = 10;

constexpr int BLOCKS  = 1024;
constexpr int NWAVES  = BLOCKS * 4;            // 4096 waves
constexpr int NPAIRS  = N_ROWS / (2 * NWAVES); // 16 pair-iterations per wave (exact)

// ws layout (doubles)
constexpr int WS_CNT  = 0;   // [1..14] high-bin counts
constexpr int WS_CSUM = 15;  // [16..29] high-bin conf sums
constexpr int WS_ASUM = 30;  // [31..44] high-bin acc sums
constexpr int WS_CS0  = 45;  // bin-0 exact conf sum (for mean rate mu)
constexpr int WS_ACC0 = 46;  // bin-0 acc count (label hits)
constexpr int WS_EXCL = 47;  // excluded elements (conf==0 or bin>=15)
constexpr int WS_NSUB = 48;  // subsampled bin-0 element count
constexpr int WS_BAND = 49;  // [49..57] band quantized-increment sums
constexpr int WS_N    = 58;

__device__ __forceinline__ float wave_fsum(float v) {
    #pragma unroll
    for (int off = 32; off >= 1; off >>= 1) v += __shfl_xor(v, off, 64);
    return v;
}
__device__ __forceinline__ void wave_fsum2(float& a, float& b) {
    #pragma unroll
    for (int off = 32; off >= 1; off >>= 1) {
        a += __shfl_xor(a, off, 64);
        b += __shfl_xor(b, off, 64);
    }
}
__device__ __forceinline__ float wave_fmax(float v) {
    #pragma unroll
    for (int off = 32; off >= 1; off >>= 1) v = fmaxf(v, __shfl_xor(v, off, 64));
    return v;
}
__device__ __forceinline__ unsigned wave_usum(unsigned v) {
    #pragma unroll
    for (int off = 32; off >= 1; off >>= 1) v += (unsigned)__shfl_xor((int)v, off, 64);
    return v;
}

__device__ __forceinline__ void load_row(const float* __restrict__ logits,
                                         const int*   __restrict__ labels,
                                         int row, int lane, bool v3,
                                         float4& r0, float4& r1, float4& r2, float4& r3, int& lb) {
    const float4* rp = reinterpret_cast<const float4*>(logits + (size_t)row * N_COLS);
    r0 = rp[lane]; r1 = rp[64 + lane]; r2 = rp[128 + lane];
    r3 = v3 ? rp[192 + lane] : make_float4(-1e30f, -1e30f, -1e30f, -1e30f);
    lb = labels[row];
}

// lean hot-path core: exp folded directly into running sum / max / min trees
__device__ __forceinline__ void row_stats(float4 A0, float4 A1, float4 A2, float4 A3, bool v3,
                                          float& q, float& mx, float& mn) {
    const float e0 =__expf(A0.x), e1 =__expf(A0.y), e2 =__expf(A0.z), e3 =__expf(A0.w);
    const float e4 =__expf(A1.x), e5 =__expf(A1.y), e6 =__expf(A1.z), e7 =__expf(A1.w);
    const float e8 =__expf(A2.x), e9 =__expf(A2.y), e10=__expf(A2.z), e11=__expf(A2.w);
    const float e12=__expf(A3.x), e13=__expf(A3.y), e14=__expf(A3.z), e15=__expf(A3.w);

    q = (((e0+e1)+(e2+e3)) + ((e4+e5)+(e6+e7)))
      + (((e8+e9)+(e10+e11)) + ((e12+e13)+(e14+e15)));

    mx = fmaxf(fmaxf(fmaxf(fmaxf(e0,e1),fmaxf(e2,e3)), fmaxf(fmaxf(e4,e5),fmaxf(e6,e7))),
               fmaxf(fmaxf(fmaxf(e8,e9),fmaxf(e10,e11)), fmaxf(fmaxf(e12,e13),fmaxf(e14,e15))));

    const float mnA = fminf(fminf(fminf(fminf(e0,e1),fminf(e2,e3)),
                                  fminf(fminf(e4,e5),fminf(e6,e7))),
                            fminf(fminf(e8,e9),fminf(e10,e11)));
    const float mnB = fminf(fminf(e12,e13),fminf(e14,e15));
    mn = v3 ? fminf(mnA, mnB) : mnA;
}

// cold path: band stats for a subsampled common row (reloads row from global)
__device__ void sub_row_band(const float* __restrict__ logits, int row, int lane, bool v3,
                             float inv, unsigned& nsubc, float band[NBANDS]) {
    const float4* rp = reinterpret_cast<const float4*>(logits + (size_t)row * N_COLS);
    float4 a0 = rp[lane], a1 = rp[64 + lane], a2 = rp[128 + lane];
    float4 a3 = v3 ? rp[192 + lane] : make_float4(-1e30f, -1e30f, -1e30f, -1e30f);
    float cf[16];
    cf[0] =__expf(a0.x)*inv; cf[1] =__expf(a0.y)*inv; cf[2] =__expf(a0.z)*inv; cf[3] =__expf(a0.w)*inv;
    cf[4] =__expf(a1.x)*inv; cf[5] =__expf(a1.y)*inv; cf[6] =__expf(a1.z)*inv; cf[7] =__expf(a1.w)*inv;
    cf[8] =__expf(a2.x)*inv; cf[9] =__expf(a2.y)*inv; cf[10]=__expf(a2.z)*inv; cf[11]=__expf(a2.w)*inv;
    cf[12]=__expf(a3.x)*inv; cf[13]=__expf(a3.y)*inv; cf[14]=__expf(a3.z)*inv; cf[15]=__expf(a3.w)*inv;
    nsubc += v3 ? 16u : 12u;                      // pads: exp(-1e30)=0 -> rint 0
    #pragma unroll
    for (int b = 0; b < NBANDS; ++b) {
        const float c = (float)(1 << (13 - b));
        const float r0=(rintf(cf[0]*c)+rintf(cf[1]*c))+(rintf(cf[2]*c)+rintf(cf[3]*c));
        const float r1=(rintf(cf[4]*c)+rintf(cf[5]*c))+(rintf(cf[6]*c)+rintf(cf[7]*c));
        const float r2=(rintf(cf[8]*c)+rintf(cf[9]*c))+(rintf(cf[10]*c)+rintf(cf[11]*c));
        const float r3=(rintf(cf[12]*c)+rintf(cf[13]*c))+(rintf(cf[14]*c)+rintf(cf[15]*c));
        band[b] += (r0+r1)+(r2+r3);
    }
}

// cold exact path: reference searchsorted semantics, max-subtracted softmax
__device__ void rare_row(const float* __restrict__ logits, int row, int lab,
                         bool sub, int lane, bool v3,
                         float& csum0, unsigned& acc0, unsigned& excl, unsigned& nsubc,
                         float band[NBANDS],
                         float* s_csum, unsigned* s_cnt, unsigned* s_asum) {
    const float delta = 1.0f / 15.0f;
    const float4* rp = reinterpret_cast<const float4*>(logits + (size_t)row * N_COLS);
    float4 a0 = rp[lane], a1 = rp[64 + lane], a2 = rp[128 + lane];
    float4 a3 = v3 ? rp[192 + lane] : make_float4(-1e30f, -1e30f, -1e30f, -1e30f);
    float x[16] = {a0.x,a0.y,a0.z,a0.w, a1.x,a1.y,a1.z,a1.w,
                   a2.x,a2.y,a2.z,a2.w, a3.x,a3.y,a3.z,a3.w};
    float m = x[0];
    #pragma unroll
    for (int i = 1; i < 16; ++i) m = fmaxf(m, x[i]);
    m = wave_fmax(m);
    float e2[16], s2 = 0.f;
    #pragma unroll
    for (int i = 0; i < 16; ++i) { e2[i] = __expf(x[i] - m); s2 += e2[i]; }
    s2 = wave_fsum(s2);
    const float inv2 = 1.0f / s2;
    #pragma unroll
    for (int i = 0; i < 16; ++i) {
        const int col = (i >> 2) * 256 + lane * 4 + (i & 3);
        if (col < N_COLS) {
            const float conf = e2[i] * inv2;
            int k = (int)(conf * 15.0f);
            if (k > 15) k = 15;
            const float bk  = (float)k * delta;
            const float bk1 = (float)(k + 1) * delta;
            if (conf <= bk)      k -= 1;
            else if (conf > bk1) k += 1;
            const bool a = (col == lab);
            if (k == 0) {
                csum0 += conf;
                if (a) acc0 += 1u;
                if (sub) {
                    nsubc += 1u;
                    #pragma unroll
                    for (int b = 0; b < NBANDS; ++b)
                        band[b] += rintf(conf * (float)(1 << (13 - b)));
                }
            } else if (k >= 1 && k < NBINS) {
                atomicAdd(&s_cnt[k], 1u);
                atomicAdd(&s_csum[k], conf);
                if (a) atomicAdd(&s_asum[k], 1u);
            } else {
                excl += 1u;   // conf==0 or bin>=15: excluded by reference
            }
        }
    }
}

__global__ __launch_bounds__(256, 4) void ece_pass(const float* __restrict__ logits,
                                                   const int*   __restrict__ labels,
                                                   double*      __restrict__ g) {
    __shared__ float    s_csum[NBINS];
    __shared__ unsigned s_cnt [NBINS];
    __shared__ unsigned s_asum[NBINS];
    const int tid = threadIdx.x;
    if (tid < NBINS) { s_csum[tid] = 0.f; s_cnt[tid] = 0u; s_asum[tid] = 0u; }
    __syncthreads();

    const int lane = tid & 63;
    const int wid  = tid >> 6;
    const int gwave = (blockIdx.x << 2) | wid;
    const bool v3 = lane < 58;                  // 250 = 64*3 + 58

    float    csum0 = 0.f;
    unsigned acc0 = 0u, excl = 0u, nsubc = 0u;
    float band[NBANDS];
    #pragma unroll
    for (int b = 0; b < NBANDS; ++b) band[b] = 0.f;

    // classification thresholds (conservative: near-boundary rows -> exact path)
    const float THR_HI = 0.066600f;   // just below 1/15
    const float THR_LO = 1e-35f;      // near-zero guard

    int rowA = gwave;
    int rowB = gwave + NWAVES;
    float4 A0,A1,A2,A3, B0,B1,B2,B3; int labA, labB;
    load_row(logits, labels, rowA, lane, v3, A0,A1,A2,A3, labA);
    load_row(logits, labels, rowB, lane, v3, B0,B1,B2,B3, labB);

    for (int itp = 0; itp < NPAIRS; ++itp) {
        // prefetch next pair while computing this one
        float4 C0,C1,C2,C3, D0,D1,D2,D3; int labC = 0, labD = 0;
        const int rowC = rowA + 2 * NWAVES;
        const int rowD = rowB + 2 * NWAVES;
        if (itp + 1 < NPAIRS) {
            load_row(logits, labels, rowC, lane, v3, C0,C1,C2,C3, labC);
            load_row(logits, labels, rowD, lane, v3, D0,D1,D2,D3, labD);
        }

        float qA, mxA, mnA, qB, mxB, mnB;
        row_stats(A0,A1,A2,A3, v3, qA, mxA, mnA);
        row_stats(B0,B1,B2,B3, v3, qB, mxB, mnB);

        float sA = qA, sB = qB;
        wave_fsum2(sA, sB);
        const float invA = 1.0f / sA;
        const float invB = 1.0f / sB;

        const bool rareA = __any((mxA * invA > THR_HI) || !(mnA * invA > THR_LO));
        const bool rareB = __any((mxB * invB > THR_HI) || !(mnB * invB > THR_LO));

        const bool sub = (itp & 7) == 0;        // rows A of itp 0,8 -> 8192 rows = 1/16

        if (__builtin_expect(!rareA, 1)) {
            csum0 += qA * invA;
            if (lane == ((labA >> 2) & 63)) acc0 += 1u;
            if (sub) sub_row_band(logits, rowA, lane, v3, invA, nsubc, band);
        }
        if (__builtin_expect(!rareB, 1)) {
            csum0 += qB * invB;
            if (lane == ((labB >> 2) & 63)) acc0 += 1u;
        }
        if (__builtin_expect(rareA || rareB, 0)) {
            if (rareA) rare_row(logits, rowA, labA, sub,   lane, v3, csum0, acc0, excl, nsubc, band, s_csum, s_cnt, s_asum);
            if (rareB) rare_row(logits, rowB, labB, false, lane, v3, csum0, acc0, excl, nsubc, band, s_csum, s_cnt, s_asum);
        }

        A0=C0; A1=C1; A2=C2; A3=C3; labA=labC; rowA=rowC;
        B0=D0; B1=D1; B2=D2; B3=D3; labB=labD; rowB=rowD;
    }

    // ---- wave / block / global reduction ----
    csum0 = wave_fsum(csum0);
    #pragma unroll
    for (int b = 0; b < NBANDS; ++b) band[b] = wave_fsum(band[b]);
    acc0 = wave_usum(acc0); excl = wave_usum(excl); nsubc = wave_usum(nsubc);

    __shared__ float    rf[4][NBANDS + 1];
    __shared__ unsigned ru[4][3];
    if (lane == 0) {
        rf[wid][0] = csum0;
        #pragma unroll
        for (int b = 0; b < NBANDS; ++b) rf[wid][1 + b] = band[b];
        ru[wid][0] = acc0; ru[wid][1] = excl; ru[wid][2] = nsubc;
    }
    __syncthreads();

    if (tid == 0) {
        double cs = 0, a0d = 0, ex = 0, ns = 0, bd[NBANDS];
        for (int b = 0; b < NBANDS; ++b) bd[b] = 0.0;
        for (int w = 0; w < 4; ++w) {
            cs  += (double)rf[w][0];
            a0d += (double)ru[w][0];
            ex  += (double)ru[w][1];
            ns  += (double)ru[w][2];
            for (int b = 0; b < NBANDS; ++b) bd[b] += (double)rf[w][1 + b];
        }
        atomicAdd(&g[WS_CS0],  cs);
        atomicAdd(&g[WS_ACC0], a0d);
        atomicAdd(&g[WS_EXCL], ex);
        atomicAdd(&g[WS_NSUB], ns);
        for (int b = 0; b < NBANDS; ++b) atomicAdd(&g[WS_BAND + b], bd[b]);
    }
    if (tid >= 1 && tid < NBINS) {
        if (s_cnt[tid]) {
            atomicAdd(&g[WS_CNT  + tid], (double)s_cnt[tid]);
            atomicAdd(&g[WS_CSUM + tid], (double)s_csum[tid]);
            atomicAdd(&g[WS_ASUM + tid], (double)s_asum[tid]);
        }
    }
}

__global__ void ece_final(const double* __restrict__ g, float* __restrict__ out) {
    if (threadIdx.x != 0 || blockIdx.x != 0) return;
    const double total = 131072000.0;

    double hi_cnt = 0.0;
    for (int k = 1; k < NBINS; ++k) hi_cnt += g[WS_CNT + k];
    const double n0 = total - hi_cnt - g[WS_EXCL];
    const double mu = (n0 > 0.0) ? g[WS_CS0] / n0 : 0.0;
    const double nsub = g[WS_NSUB];

    double rate[NBANDS];
    for (int b = 0; b < NBANDS; ++b)
        rate[b] = (nsub > 0.0) ? (g[WS_BAND + b] / nsub) * ldexp(1.0, (BAND_LO + b) - 23)
                               : mu;

    // mean-field walk of the reference's fp32 sequential accumulator
    double acc = 0.0, rem = n0;
    for (int itr = 0; itr < 64 && rem > 0.5; ++itr) {
        double r, edge;
        if (acc < 1024.0) { r = mu; edge = 1024.0; }
        else {
            int b = BAND_LO;
            while (b < BAND_LO + NBANDS - 1 && acc >= ldexp(1.0, b + 1)) ++b;
            r = rate[b - BAND_LO];
            edge = (b == BAND_LO + NBANDS - 1) ? 1e300 : ldexp(1.0, b + 1);
        }
        if (!(r > 1e-300)) break;                 // accumulator frozen
        const double need = (edge - acc) / r;
        if (need >= rem) { acc += rem * r; rem = 0.0; }
        else             { acc = edge; rem -= need; }
    }
    const double conf_sum0 = acc;
    const double cnt0 = (n0 < 16777216.0) ? n0 : 16777216.0;  // fp32 +1.0 saturation

    double ece = 0.0;
    if (cnt0 > 0.0)
        ece += fabs(conf_sum0 / cnt0 - g[WS_ACC0] / cnt0) * (cnt0 / total);
    for (int k = 1; k < NBINS; ++k) {
        const double c = g[WS_CNT + k];
        if (c > 0.0)
            ece += fabs(g[WS_CSUM + k] / c - g[WS_ASUM + k] / c) * (c / total);
    }
    out[0] = (float)ece;
}

extern "C" void kernel_launch(void* const* d_in, const int* in_sizes, int n_in,
                              void* d_out, int out_size, void* d_ws, size_t ws_size,
                              hipStream_t stream) {
    const float* logits = (const float*)d_in[0];
    const int*   labels = (const int*)d_in[1];
    float*       out    = (float*)d_out;
    double*      g      = (double*)d_ws;

    hipMemsetAsync(g, 0, WS_N * sizeof(double), stream);

    ece_pass<<<BLOCKS, 256, 0, stream>>>(logits, labels, g);
    ece_final<<<1, 64, 0, stream>>>(g, out);
}